// Round 5
// baseline (475.635 us; speedup 1.0000x reference)
//
#include <hip/hip_runtime.h>

// ============================================================================
// CharLevelEncoder R10: double wave parallelism (4 waves/SIMD, was 2).
// R5-R9 post-mortem: FETCH/WRITE "excess" (~137 MB each way) is invariant
// across kernels with 2x different register demand -> counter artifact, NOT
// scratch. Trustworthy signal: ~41k cycles/step vs ~6k modeled compute at
// Occupancy 22% (2 waves/SIMD) -> ~85% stall; latency hiding is the limiter.
// Fix: 1024-thread megablocks (16 waves/CU = 4 waves/SIMD):
//  - wave w owns h-dims [w*16,w*16+16) x 4 gates: wreg = kb0-3 x 4g = 32 VGPR
//    (maps to packed frags at w_old=w>>1, nt_old=2g+(w&1) -> no prep change);
//  - kb4-7 weights in LDS (128 KB) shared by all 16 waves;
//  - accs 16 + creg 16 + working set -> peak ~110 <= 128-reg 4-wave budget;
//  - per-wave VALU/MFMA halves; total work, LDS (148 KB), numerics unchanged.
// ============================================================================

#define NW 32768

typedef __attribute__((ext_vector_type(8))) short short8;
typedef __attribute__((ext_vector_type(4))) float f32x4;
typedef __attribute__((ext_vector_type(4))) int i32x4;
typedef __attribute__((ext_vector_type(4))) unsigned short u16x4;

#define MFMA16(a,b,c) __builtin_amdgcn_mfma_f32_16x16x32_bf16(a,b,c,0,0,0)
#define MFMAI8(a,b,c) __builtin_amdgcn_mfma_i32_16x16x32_i8(a,b,c,0,0,0)

// ---- workspace layout (bytes) ----
#define O_ORDER 0           // i32[32768] sorted word ids (asc len)
#define O_SLEN  131072      // i32[32768] sorted lengths
#define O_WPK   262144      // i8 packed W_hh' fragments (262144)
#define O_USTP  524288      // f32[1024] u' = rowmax(whh)/(127*127)
#define O_WLIN  528384      // bf16 packed W_lin fragments (262144)
#define O_PX    790528      // bf16[256][256][4] x-proj+bias table (524288)
#define O_BH    1314816     // i32[128][16] per-block length histograms
#define O_BASE  1323008     // i32[128][16] scatter bases
// total 1331200 B

__device__ inline unsigned short f2b(float f) {   // fp32 -> bf16 RNE
  unsigned u = __builtin_bit_cast(unsigned, f);
  u = u + 0x7fffu + ((u >> 16) & 1u);
  return (unsigned short)(u >> 16);
}
__device__ inline float b2f(unsigned short u) {
  return __builtin_bit_cast(float, ((unsigned)u) << 16);
}
__device__ inline float fsigm(float x) {
  float e = __builtin_amdgcn_exp2f(-1.44269504f * x);
  return __builtin_amdgcn_rcpf(1.0f + e);
}
__device__ inline float ftanh(float x) {
  float e = __builtin_amdgcn_exp2f(2.88539008f * x);
  return 1.0f - 2.0f * __builtin_amdgcn_rcpf(e + 1.0f);
}

// ---- prep0: per-row scales over W_hh only (x-path is exact) ----
__global__ void k_prep0(const float* __restrict__ whh, unsigned char* __restrict__ ws) {
  int i = blockIdx.x * 256 + threadIdx.x;      // 0..1023
  const f32x4* r4 = (const f32x4*)(whh + i * 256);
  float mx = 0.f;
  #pragma unroll 8
  for (int k4 = 0; k4 < 64; ++k4) {
    f32x4 v = r4[k4];
    mx = fmaxf(mx, fmaxf(fmaxf(fabsf(v[0]), fabsf(v[1])),
                         fmaxf(fabsf(v[2]), fabsf(v[3]))));
  }
  ((float*)(ws + O_USTP))[i] = mx / (127.f * 127.f);
}

// ---- prep1: pack W_hh' i8 fragments + W_lin bf16 fragments ----
__global__ void k_prep1(const float* __restrict__ whh, const float* __restrict__ wlin,
                        unsigned char* __restrict__ ws) {
  int i = blockIdx.x * 256 + threadIdx.x;
  if (i < 262144) {
    int j = i & 7, lane = (i >> 3) & 63, t2 = i >> 9;
    int nt = t2 & 7, u2 = t2 >> 3;
    int kb = u2 & 7, w = u2 >> 3;
    int n = (nt >> 1) * 256 + w * 32 + (nt & 1) * 16 + (lane & 15);
    int k = kb * 32 + (lane >> 4) * 8 + j;
    float v = whh[n * 256 + k];
    float ustep = ((const float*)(ws + O_USTP))[n] * 127.f;   // rowmax/127
    float qf = (ustep > 0.f) ? v / ustep : 0.f;
    int q = (int)__builtin_rintf(qf);
    q = q < -127 ? -127 : (q > 127 ? 127 : q);
    ((signed char*)(ws + O_WPK))[i] = (signed char)q;
    return;
  }
  int i2 = i - 262144;                  // < 131072, W_lin pack (verified R4)
  {
    int j = i2 & 7, lane = (i2 >> 3) & 63, t3 = i2 >> 9;
    int kf = t3 & 15, nn = t3 >> 4;
    int n = (nn >> 2) * 64 + (nn & 3) * 16 + (lane & 15);
    int k = kf * 32 + (lane >> 4) * 8 + j;
    ((unsigned short*)(ws + O_WLIN))[i2] = f2b(wlin[n * 512 + k]);
  }
}

// ---- prep2: PX[c][hd][g] = sum_k wih[g*256+hd][k]*ech[c][k] + bih+bhh (bf16) ----
__global__ void k_prep2(const float* __restrict__ wih, const float* __restrict__ ech,
                        const float* __restrict__ bih, const float* __restrict__ bhh,
                        unsigned char* __restrict__ ws) {
  int id = blockIdx.x * 256 + threadIdx.x;     // 0..262143
  int c = id >> 10, n = id & 1023;
  const f32x4* w4 = (const f32x4*)(wih + n * 64);
  const f32x4* e4 = (const f32x4*)(ech + c * 64);
  float acc = bih[n] + bhh[n];
  #pragma unroll
  for (int k4 = 0; k4 < 16; ++k4) {
    f32x4 a = w4[k4], e = e4[k4];
    acc += a[0] * e[0] + a[1] * e[1] + a[2] * e[2] + a[3] * e[3];
  }
  ((unsigned short*)(ws + O_PX))[((c << 8) + (n & 255)) * 4 + (n >> 8)] = f2b(acc);
}

// ---- multi-block counting sort by length: hist -> scan -> scatter ----
__global__ void k_hist(const int* __restrict__ lens, unsigned char* __restrict__ ws) {
  __shared__ int h[16];
  int t = threadIdx.x, b = blockIdx.x;
  if (t < 16) h[t] = 0;
  __syncthreads();
  int wid = b * 256 + t;
  int l = lens[wid]; l = l < 1 ? 1 : (l > 16 ? 16 : l);
  atomicAdd(&h[l - 1], 1);
  __syncthreads();
  if (t < 16) ((int*)(ws + O_BH))[b * 16 + t] = h[t];
}

__global__ void k_scan(unsigned char* __restrict__ ws) {
  __shared__ int tot[16], g[16];
  int t = threadIdx.x;
  const int* bh = (const int*)(ws + O_BH);
  int* base = (int*)(ws + O_BASE);
  if (t < 16) {
    int s = 0;
    for (int b = 0; b < 128; ++b) s += bh[b * 16 + t];
    tot[t] = s;
  }
  __syncthreads();
  if (t == 0) { int a = 0; for (int i = 0; i < 16; ++i) { g[i] = a; a += tot[i]; } }
  __syncthreads();
  if (t < 16) {
    int run = g[t];
    for (int b = 0; b < 128; ++b) { base[b * 16 + t] = run; run += bh[b * 16 + t]; }
  }
}

__global__ void k_scatter(const int* __restrict__ lens, unsigned char* __restrict__ ws) {
  __shared__ int cnt[16];
  int t = threadIdx.x, b = blockIdx.x;
  if (t < 16) cnt[t] = 0;
  __syncthreads();
  int wid = b * 256 + t;
  int l = lens[wid]; l = l < 1 ? 1 : (l > 16 ? 16 : l);
  int rank = atomicAdd(&cnt[l - 1], 1);
  int p = ((const int*)(ws + O_BASE))[b * 16 + (l - 1)] + rank;
  ((int*)(ws + O_ORDER))[p] = wid;
  ((int*)(ws + O_SLEN))[p] = l;
}

// ---- main persistent kernel: 256 blocks x 1024 threads (16 waves/CU) ----
__global__ __launch_bounds__(1024)
void k_main(
    const int* __restrict__ cidx, const float* __restrict__ wemb,
    const float* __restrict__ blin, float* __restrict__ outp,
    const unsigned char* __restrict__ ws) {
  extern __shared__ signed char smem[];
  // WL: W_hh' kb 4-7 fragments [kb4][w_old][nt_old][lane][8]  128 KB
  signed char (*WL)[8][8][64][8] = (signed char (*)[8][8][64][8])smem;
  // Xb: single-buffered h-state, i8 [mt][kb][lane][8]  16 KB
  signed char (*Xb)[8][64][8] = (signed char (*)[8][64][8])(smem + 131072);
  int (*CW)[16] = (int (*)[16])(smem + 131072 + 16384);   // 4 KB

  const int tid = threadIdx.x, b = blockIdx.x;
  const int w = tid >> 6, lane = tid & 63;     // w in 0..15
  const int q = lane >> 4, l15 = lane & 15;
  const int wo = w >> 1, wp = w & 1;           // map to packed-frag coords

  const int* order = (const int*)(ws + O_ORDER);
  const int* slen  = (const int*)(ws + O_SLEN);
  const signed char* wpk = (const signed char*)(ws + O_WPK);
  const float* upt = (const float*)(ws + O_USTP);
  const unsigned short* wlin = (const unsigned short*)(ws + O_WLIN);
  const unsigned short* pxt = (const unsigned short*)(ws + O_PX);

  // ---- prologue: W kb0-3 for this wave's 4 gate-frags -> VGPR (32 regs) ----
  // wave w owns h-dims [w*16, w*16+16); frag(g) = packed (wo, kb, nt=2g+wp)
  long wreg[4][4];
  #pragma unroll
  for (int kb = 0; kb < 4; ++kb)
    #pragma unroll
    for (int g = 0; g < 4; ++g)
      wreg[kb][g] =
          *(const long*)(wpk + (((wo * 8 + kb) * 8 + (2 * g + wp)) * 64 + lane) * 8);

  {  // W kb4-7 -> LDS (128 KB), 16384 longs / 1024 threads
    long* wlds = (long*)smem;
    const long* wsrc = (const long*)wpk;
    #pragma unroll
    for (int ii = 0; ii < 16; ++ii) {
      int f = ii * 1024 + tid;
      int lane_ = f & 63, r = f >> 6;
      int nt_ = r & 7, r2 = r >> 3;
      int w_ = r2 & 7, kb4 = r2 >> 3;
      wlds[f] = wsrc[((w_ * 8 + 4 + kb4) * 8 + nt_) * 64 + lane_];
    }
  }

  const int hd0 = w * 16 + l15;          // this lane's h-dim
  float uq[4];
  #pragma unroll
  for (int g = 0; g < 4; ++g) uq[g] = upt[g * 256 + hd0];

  // ---- two balanced slices: {b, 511-b} ----
  for (int sl = 0; sl < 2; ++sl) {
    const int s = sl ? (511 - b) : b;
    const int base = 64 * s;
    __syncthreads();                    // WL staged / prev epilogue done
    { // zero Xb h-state (2048 longs)
      long* p = (long*)&Xb[0][0][0][0];
      p[tid] = 0L; p[tid + 1024] = 0L;
    }
    if (tid < 256) {                    // this slice's char indices
      int m = tid >> 2, part = tid & 3;
      int wid = order[base + m];
      *(i32x4*)&CW[m][part * 4] =
          __builtin_nontemporal_load((const i32x4*)(cidx + wid * 16 + part * 4));
    }
    int tmax[4]; unsigned lenpk[4];
    #pragma unroll
    for (int mt = 0; mt < 4; ++mt) {
      int pbm = base + 16 * mt;
      tmax[mt] = slen[pbm + 15];
      unsigned l0 = (unsigned)slen[pbm + q * 4 + 0];
      unsigned l1 = (unsigned)slen[pbm + q * 4 + 1];
      unsigned l2 = (unsigned)slen[pbm + q * 4 + 2];
      unsigned l3 = (unsigned)slen[pbm + q * 4 + 3];
      lenpk[mt] = l0 | (l1 << 8) | (l2 << 16) | (l3 << 24);
    }
    const int Tm = tmax[3];
    __syncthreads();                    // CW + zeroing visible

    float creg[4][4];                   // [mt][r] cell state at (word, hd0)
    unsigned hreg[4];                   // [mt] packed h bytes (r lanes)
    #pragma unroll
    for (int mt = 0; mt < 4; ++mt) {
      hreg[mt] = 0u;
      #pragma unroll
      for (int r = 0; r < 4; ++r) creg[mt][r] = 0.f;
    }

    for (int t = 0; t < Tm; ++t) {
      #pragma unroll
      for (int mt = 0; mt < 4; ++mt) {
        if (mt != 3 && t >= tmax[mt]) continue;   // wave-uniform
        int cc[4];
        #pragma unroll
        for (int r = 0; r < 4; ++r) cc[r] = CW[mt * 16 + q * 4 + r][t] & 255;
        u16x4 pb[4];                    // [r] = (i,f,g,o) bf16 at (cc, hd0)
        #pragma unroll
        for (int r = 0; r < 4; ++r)
          pb[r] = *(const u16x4*)&pxt[((cc[r] << 8) + hd0) * 4];
        i32x4 a0 = (i32x4)0, a1 = (i32x4)0, a2 = (i32x4)0, a3 = (i32x4)0;
        #pragma unroll
        for (int kb = 0; kb < 4; ++kb) {
          long A = *(const long*)&Xb[mt][kb][lane][0];
          a0 = MFMAI8(A, wreg[kb][0], a0);
          a1 = MFMAI8(A, wreg[kb][1], a1);
          a2 = MFMAI8(A, wreg[kb][2], a2);
          a3 = MFMAI8(A, wreg[kb][3], a3);
        }
        #pragma unroll
        for (int kb = 4; kb < 8; ++kb) {          // B from LDS
          long A = *(const long*)&Xb[mt][kb][lane][0];
          long b0 = *(const long*)&WL[kb - 4][wo][0 + wp][lane][0];
          long b1 = *(const long*)&WL[kb - 4][wo][2 + wp][lane][0];
          long b2 = *(const long*)&WL[kb - 4][wo][4 + wp][lane][0];
          long b3 = *(const long*)&WL[kb - 4][wo][6 + wp][lane][0];
          a0 = MFMAI8(A, b0, a0);
          a1 = MFMAI8(A, b1, a1);
          a2 = MFMAI8(A, b2, a2);
          a3 = MFMAI8(A, b3, a3);
        }
        // gates + LSTM update; C-layout row(word) = q*4+r, col = l15 (= hd0)
        unsigned hp = 0;
        #pragma unroll
        for (int r = 0; r < 4; ++r) {
          float gi = (float)a0[r] * uq[0] + b2f(pb[r][0]);
          float gf = (float)a1[r] * uq[1] + b2f(pb[r][1]);
          float gg = (float)a2[r] * uq[2] + b2f(pb[r][2]);
          float go = (float)a3[r] * uq[3] + b2f(pb[r][3]);
          float si = fsigm(gi), sf = fsigm(gf);
          float sg = ftanh(gg), so = fsigm(go);
          float cold = creg[mt][r];
          float cn = sf * cold + si * sg;
          float hn = so * ftanh(cn);
          int lene = (int)((lenpk[mt] >> (8 * r)) & 255u);
          bool live = t < lene;
          creg[mt][r] = live ? cn : cold;
          int hq = (int)__builtin_rintf(127.f * hn);   // |hn|<1 -> no clamp
          unsigned ob = (hreg[mt] >> (8 * r)) & 255u;
          unsigned nb = live ? ((unsigned)hq & 255u) : ob;
          hp |= nb << (8 * r);
        }
        hreg[mt] = hp;
      } // mt
      __syncthreads();                  // all Xb reads of step t done

      // h write-back: wave w owns h-dims hd0 -> kb = wo, v = wp*16 + l15
      #pragma unroll
      for (int mt = 0; mt < 4; ++mt) {
        if (mt != 3 && t >= tmax[mt]) continue;
        int row16 = 16 * (wp * 2 + (l15 >> 3));
        #pragma unroll
        for (int r = 0; r < 4; ++r)
          Xb[mt][wo][(q * 4 + r) + row16][l15 & 7] =
              (signed char)((hreg[mt] >> (8 * r)) & 255u);
      }
      __syncthreads();                  // writes visible for step t+1
    } // t

    // ---- fused final linear for this slice (bf16 MFMA) ----
    // 16 waves = (mh2 = w>>2) word-group x (nw = w&3) col-block
    const int mh2 = w >> 2, nw = w & 3;
    float blv[4];
    #pragma unroll
    for (int nt = 0; nt < 4; ++nt) blv[nt] = blin[nw * 64 + nt * 16 + l15];
    int widA = order[base + mh2 * 16 + l15];
    f32x4 fac[4];
    #pragma unroll
    for (int nt = 0; nt < 4; ++nt) fac[nt] = 0.0f;

    #pragma unroll
    for (int kf = 0; kf < 16; ++kf) {
      short8 Bn[4];
      #pragma unroll
      for (int nt = 0; nt < 4; ++nt)
        Bn[nt] = ((const short8*)wlin)[((nw * 4 + nt) * 16 + kf) * 64 + lane];
      short8 Am;
      if (kf < 8) {                     // word_emb fp32 -> bf16
        const f32x4* pa = (const f32x4*)(wemb + widA * 256 + kf * 32 + q * 8);
        f32x4 f0 = __builtin_nontemporal_load(pa);
        f32x4 f1 = __builtin_nontemporal_load(pa + 1);
        Am[0] = (short)f2b(f0[0]); Am[1] = (short)f2b(f0[1]);
        Am[2] = (short)f2b(f0[2]); Am[3] = (short)f2b(f0[3]);
        Am[4] = (short)f2b(f1[0]); Am[5] = (short)f2b(f1[1]);
        Am[6] = (short)f2b(f1[2]); Am[7] = (short)f2b(f1[3]);
      } else {                          // final h from Xb i8 -> bf16
        long ch = *(const long*)&Xb[mh2][kf - 8][lane][0];
        #pragma unroll
        for (int j = 0; j < 8; ++j) {
          int v = (int)(signed char)((ch >> (8 * j)) & 255);
          Am[j] = (short)f2b((float)v * (1.f / 127.f));
        }
      }
      #pragma unroll
      for (int nt = 0; nt < 4; ++nt)
        fac[nt] = MFMA16(Am, Bn[nt], fac[nt]);
    }
    #pragma unroll
    for (int r = 0; r < 4; ++r) {
      int wid = order[base + mh2 * 16 + q * 4 + r];
      float* po = outp + wid * 256 + nw * 64 + l15;
      #pragma unroll
      for (int nt = 0; nt < 4; ++nt) {
        float v = fac[nt][r] + blv[nt];
        __builtin_nontemporal_store(v > 0.f ? v : 0.f, po + nt * 16);
      }
    }
  } // slice
}

extern "C" void kernel_launch(void* const* d_in, const int* in_sizes, int n_in,
                              void* d_out, int out_size, void* d_ws, size_t ws_size,
                              hipStream_t stream) {
  const int*   cidx = (const int*)d_in[0];
  const int*   clen = (const int*)d_in[1];
  const float* wemb = (const float*)d_in[2];
  const float* ech  = (const float*)d_in[3];
  const float* wih  = (const float*)d_in[4];
  const float* whh  = (const float*)d_in[5];
  const float* bih  = (const float*)d_in[6];
  const float* bhh  = (const float*)d_in[7];
  const float* wlin = (const float*)d_in[8];
  const float* blin = (const float*)d_in[9];
  float* outp = (float*)d_out;
  unsigned char* ws = (unsigned char*)d_ws;

  k_prep0<<<4, 256, 0, stream>>>(whh, ws);
  k_prep1<<<1536, 256, 0, stream>>>(whh, wlin, ws);
  k_prep2<<<1024, 256, 0, stream>>>(wih, ech, bih, bhh, ws);
  k_hist<<<128, 256, 0, stream>>>(clen, ws);
  k_scan<<<1, 64, 0, stream>>>(ws);
  k_scatter<<<128, 256, 0, stream>>>(clen, ws);
  k_main<<<256, 1024, 151552, stream>>>(cidx, wemb, blin, outp, ws);
}